// Round 7
// baseline (63.737 us; speedup 1.0000x reference)
//
#include <hip/hip_runtime.h>
#include <cstddef>

#define B_ 8
#define C_ 128
#define K_ 128
#define L_ 2048

static constexpr float SCALE = 0.08838834764831843f; // 1/sqrt(128)

typedef unsigned short u16;
typedef __attribute__((ext_vector_type(8))) short bf16x8;
typedef __attribute__((ext_vector_type(4))) unsigned short u16x4;
typedef __attribute__((ext_vector_type(4))) unsigned int u32x4;
typedef __attribute__((ext_vector_type(4))) float f32x4;
typedef __attribute__((ext_vector_type(16))) float f32x16;

__device__ __forceinline__ u16 f2bf(float x) {
    unsigned u = __builtin_bit_cast(unsigned, x);
    u += 0x7FFFu + ((u >> 16) & 1u);     // round-to-nearest-even
    return (u16)(u >> 16);
}

__device__ __forceinline__ unsigned cvtpk(float lo, float hi) {
    unsigned r;
    asm("v_cvt_pk_bf16_f32 %0, %1, %2" : "=v"(r) : "v"(lo), "v"(hi));
    return r;
}
// v_permlane32_swap_b32 a, b:  a' = {a.lo, b.lo},  b' = {a.hi, b.hi}
__device__ __forceinline__ void plswap(unsigned& a, unsigned& b) {
    asm volatile("v_permlane32_swap_b32 %0, %1" : "+v"(a), "+v"(b));
}

#define MFMA32 __builtin_amdgcn_mfma_f32_32x32x16_bf16

// Fragment-ready layouts (all loads are base + lane*16B):
//  qF/kF: [b][tile32][ks(8)][hl(2)][lane32][8]   tile = position/32, k = ks*16+hl*8+j
//  vF:    [b][mtile32][ob(4)][t(2)][hl(2)][lane32][8]
//         o = ob*32+lane, m = mtile*32 + t*16 + hl*8 + j

// ---------------------------------------------------------------------------
// K1: MFMA projections into fragment-ready layouts, x staged through LDS.
// grid 768 flattened: b = bid&7 (XCD-pinned so frag writes stay in the L2
// that rs/wpv for batch b read), p = (bid>>3)>>5, l0 = ((bid>>3)&31)*64.
// block 256 = 4 waves.
// ---------------------------------------------------------------------------
__global__ __launch_bounds__(256) void proj_kernel(
    const float* __restrict__ x1, const float* __restrict__ x2,
    const float* __restrict__ Wq, const float* __restrict__ bq,
    const float* __restrict__ Wk, const float* __restrict__ bk,
    const float* __restrict__ Wv, const float* __restrict__ bv,
    u16* __restrict__ qF, u16* __restrict__ kF, u16* __restrict__ vF)
{
    const int bid = blockIdx.x;
    const int b   = bid & 7;
    const int r   = bid >> 3;            // 0..95
    const int p   = r >> 5;              // 0..2
    const int l0  = (r & 31) * 64;
    const float* W    = (p == 0) ? Wq : (p == 1) ? Wk : Wv;
    const float* bias = (p == 0) ? bq : (p == 1) ? bk : bv;
    const float* X    = (p == 0) ? x1 : x2;

    __shared__ u16 Wls[128 * 136];   // [k][c], stride 136 shorts (pad 8)
    __shared__ u16 xls[64 * 136];    // [l_local][c], same padded stride
    const int tid = threadIdx.x;

    // ---- W staging (f32 -> bf16), coalesced float4
    for (int i = tid; i < 4096; i += 256) {
        float4 v = ((const float4*)W)[i];
        int e = i << 2; int row = e >> 7; int colc = e & 127;
        u16x4 pk = { f2bf(v.x), f2bf(v.y), f2bf(v.z), f2bf(v.w) };
        *(u16x4*)&Wls[row * 136 + colc] = pk;
    }

    // ---- x staging: read coalesced along l, write transposed bf16 tile [l][c]
    {
        const int lane = tid & 63;
        const int crow = tid >> 6;           // 4 c-rows in flight
        const float* xp = X + ((size_t)b * C_ + crow) * L_ + l0 + lane;
        #pragma unroll 4
        for (int c0 = crow; c0 < 128; c0 += 4) {
            xls[lane * 136 + c0] = f2bf(*xp);
            xp += 4 * (size_t)L_;
        }
    }
    __syncthreads();

    const int w = tid >> 6, l = tid & 63;
    const int lr = l & 15, lg = l >> 4;
    const int lrow = l0 + w * 16 + lr;       // global position
    const int lloc = w * 16 + lr;            // LDS-local row

    bf16x8 xfr[4];
    #pragma unroll
    for (int s = 0; s < 4; ++s)
        xfr[s] = *(const bf16x8*)&xls[lloc * 136 + s * 32 + lg * 8];

    const int hl2 = lg >> 1, j0 = (lg & 1) * 4;

    for (int kt = 0; kt < 8; ++kt) {
        bf16x8 wfr[4];
        #pragma unroll
        for (int s = 0; s < 4; ++s)
            wfr[s] = *(const bf16x8*)&Wls[(kt * 16 + lr) * 136 + s * 32 + lg * 8];
        f32x4 acc = {0.f, 0.f, 0.f, 0.f};
        if (p < 2) {
            // D[k][pos]: col(lr)=pos-local, row(lg*4+r)=k = kt*16+lg*4+r
            #pragma unroll
            for (int s = 0; s < 4; ++s)
                acc = __builtin_amdgcn_mfma_f32_16x16x32_bf16(wfr[s], xfr[s], acc, 0, 0, 0);
            u16x4 pk;
            #pragma unroll
            for (int rr = 0; rr < 4; ++rr)
                pk[rr] = f2bf(acc[rr] + bias[kt * 16 + lg * 4 + rr]);
            const int qt = lrow >> 5, qloc = lrow & 31;
            u16* dstp = ((p == 0) ? qF : kF)
                + (((size_t)b * 64 + qt) * 8 + kt) * 512 + hl2 * 256 + qloc * 8 + j0;
            *(u16x4*)dstp = pk;
        } else {
            // D[pos][o]: col(lr)=o-part, row(lg*4+r)=pos = lrow-part
            #pragma unroll
            for (int s = 0; s < 4; ++s)
                acc = __builtin_amdgcn_mfma_f32_16x16x32_bf16(xfr[s], wfr[s], acc, 0, 0, 0);
            const int o = kt * 16 + lr;
            const float bo = bias[o];
            u16x4 pk;
            #pragma unroll
            for (int rr = 0; rr < 4; ++rr)
                pk[rr] = f2bf(acc[rr] + bo);
            const int mt  = (l0 >> 5) + ((w * 16 + lg * 4) >> 5);
            const int t   = w & 1;
            const int ob  = kt >> 1;
            const int oloc = (kt & 1) * 16 + lr;
            u16* dstp = vF + ((size_t)b * 64 + mt) * 4096
                + ob * 1024 + t * 512 + hl2 * 256 + oloc * 8 + j0;
            *(u16x4*)dstp = pk;
        }
    }
}

// ---------------------------------------------------------------------------
// K2a: rs precompute. QK + exp + colsum only; writes rs[b][q] = 1/sum.
// grid 512 (b = bid&7 -> XCD-pinned), block 256 = 4 waves; wave owns 512 m.
// (proven in round 3; numerics identical)
// ---------------------------------------------------------------------------
__global__ __launch_bounds__(256, 2) void rs_kernel(
    const u16* __restrict__ qF, const u16* __restrict__ kF,
    float* __restrict__ rsb)
{
    __shared__ float cred[4 * 32];

    const int bid = blockIdx.x;
    const int b   = bid & 7;
    const int qt  = bid >> 3;
    const int tid = threadIdx.x;
    const int w   = tid >> 6;             // 0..3
    const int l   = tid & 63;
    const int col = l & 31;
    const int hl  = l >> 5;

    bf16x8 qf[8];
    {
        const u16* qp = qF + (((size_t)b * 64 + qt) * 8) * 512 + l * 8;
        #pragma unroll
        for (int ks = 0; ks < 8; ++ks)
            qf[ks] = *(const bf16x8*)(qp + ks * 512);
    }

    const u16* kbase = kF + (((size_t)b * 64 + w * 16) * 8) * 512 + l * 8;

    bf16x8 kA[8], kB[8];
    auto LK = [&](bf16x8 (&d)[8], int it) {
        const u16* ka = kbase + (size_t)it * 4096;
        #pragma unroll
        for (int j = 0; j < 8; ++j)
            d[j] = *(const bf16x8*)(ka + j * 512);
    };

    float csum = 0.f;
    LK(kA, 0);
    #pragma unroll
    for (int it = 0; it < 16; ++it) {
        bf16x8* kf = (it & 1) ? kB : kA;
        bf16x8 (&kn)[8] = (it & 1) ? kA : kB;
        f32x16 sa = {}, sb = {};
        sa = MFMA32(kf[0], qf[0], sa, 0, 0, 0); sb = MFMA32(kf[4], qf[4], sb, 0, 0, 0);
        sa = MFMA32(kf[1], qf[1], sa, 0, 0, 0); sb = MFMA32(kf[5], qf[5], sb, 0, 0, 0);
        sa = MFMA32(kf[2], qf[2], sa, 0, 0, 0); sb = MFMA32(kf[6], qf[6], sb, 0, 0, 0);
        sa = MFMA32(kf[3], qf[3], sa, 0, 0, 0); sb = MFMA32(kf[7], qf[7], sb, 0, 0, 0);
        if (it < 15) LK(kn, it + 1);

        float e[16];
        #pragma unroll
        for (int r = 0; r < 16; ++r)
            e[r] = __expf((sa[r] + sb[r]) * SCALE);
        float c0 = (e[0] + e[1]) + (e[2] + e[3]);
        float c1 = (e[4] + e[5]) + (e[6] + e[7]);
        float c2 = (e[8] + e[9]) + (e[10] + e[11]);
        float c3 = (e[12] + e[13]) + (e[14] + e[15]);
        csum += (c0 + c1) + (c2 + c3);
    }

    csum += __shfl_xor(csum, 32);
    if (hl == 0) cred[w * 32 + col] = csum;
    __syncthreads();
    if (tid < 32) {
        const float s = (cred[tid] + cred[32 + tid]) + (cred[64 + tid] + cred[96 + tid]);
        rsb[(size_t)b * L_ + qt * 32 + tid] = 1.0f / s;
    }
}

// ---------------------------------------------------------------------------
// K2b: single-pass w + PV, rs known. Stores spread uniformly over the WHOLE
// kernel; issue order per iter = {V loads, QK, K-next loads, exp, wt write,
// wt read + 4 wide stores, pack, PV} -- all loads issue BEFORE the iter's
// stores, so vmcnt waits (oldest-first) never drain the store backlog.
// grid 512 (b = bid&7), block 256 = 4 waves, 2 blocks/CU resident
// (K,V single-buffered with mid-iter issue -> ~230 VGPR).
// Wave owns 512 m = 16 iters of 32 m.
// ---------------------------------------------------------------------------
__global__ __launch_bounds__(256, 2) void wpv_kernel(
    const u16* __restrict__ qF, const u16* __restrict__ kF,
    const u16* __restrict__ vF, const float* __restrict__ rsb,
    float* __restrict__ out, float* __restrict__ wout)
{
    __shared__ float scratch[2 * 128 * 36];   // 36.9 KB: wt (4x1152) in loop, red0/red1 after

    const int bid = blockIdx.x;
    const int b   = bid & 7;
    const int qt  = bid >> 3;
    const int q0  = qt * 32;
    const int tid = threadIdx.x;
    const int w   = tid >> 6;             // 0..3
    const int l   = tid & 63;
    const int col = l & 31;
    const int hl  = l >> 5;

    bf16x8 qf[8];
    {
        const u16* qp = qF + (((size_t)b * 64 + qt) * 8) * 512 + l * 8;
        #pragma unroll
        for (int ks = 0; ks < 8; ++ks)
            qf[ks] = *(const bf16x8*)(qp + ks * 512);
    }
    const float rs = rsb[(size_t)b * L_ + q0 + col];

    const u16* kbase = kF + (((size_t)b * 64 + w * 16) * 8) * 512 + l * 8;
    const u16* vbase = vF + ((size_t)b * 64 + w * 16) * 4096 + l * 8;

    f32x16 pv0 = {}, pv1 = {}, pv2 = {}, pv3 = {};

    float* wt = scratch + w * 1152;       // per-wave 32 x 36 f32 tile
    const int mr  = l >> 3;               // 0..7
    const int qc8 = (l & 7) * 4;          // 0,4,...,28

    bf16x8 kf[8], vf[8];
    {   // prologue: K for it=0
        #pragma unroll
        for (int j = 0; j < 8; ++j)
            kf[j] = *(const bf16x8*)(kbase + j * 512);
    }

    #pragma unroll
    for (int it = 0; it < 16; ++it) {
        // ---- V loads first (consumed by PV at iter end: self-prefetched)
        const u16* va = vbase + (size_t)it * 4096;
        #pragma unroll
        for (int j = 0; j < 8; ++j)
            vf[j] = *(const bf16x8*)(va + j * 512);   // vf[2s+t] = (ob=s, t)

        // ---- QK (kf loaded last iter / prologue)
        f32x16 sa = {}, sb = {};
        sa = MFMA32(kf[0], qf[0], sa, 0, 0, 0); sb = MFMA32(kf[4], qf[4], sb, 0, 0, 0);
        sa = MFMA32(kf[1], qf[1], sa, 0, 0, 0); sb = MFMA32(kf[5], qf[5], sb, 0, 0, 0);
        sa = MFMA32(kf[2], qf[2], sa, 0, 0, 0); sb = MFMA32(kf[6], qf[6], sb, 0, 0, 0);
        sa = MFMA32(kf[3], qf[3], sa, 0, 0, 0); sb = MFMA32(kf[7], qf[7], sb, 0, 0, 0);

        // ---- K for next iter (kf dead after QK; gap to next use covers L2 lat)
        if (it < 15) {
            const u16* ka = kbase + (size_t)(it + 1) * 4096;
            #pragma unroll
            for (int j = 0; j < 8; ++j)
                kf[j] = *(const bf16x8*)(ka + j * 512);
        }

        float e[16];
        #pragma unroll
        for (int r = 0; r < 16; ++r)
            e[r] = __expf((sa[r] + sb[r]) * SCALE);

        // ---- w tile: write e*rs into per-wave LDS (D rows: m = rr + 8g + 4hl)
        #pragma unroll
        for (int g = 0; g < 4; ++g)
            #pragma unroll
            for (int rr = 0; rr < 4; ++rr)
                wt[(rr + 8 * g + 4 * hl) * 36 + col] = e[4 * g + rr] * rs;

        // ---- pack unnormalized e to bf16 PV B-frags (VALU overlaps DS)
        unsigned R0 = cvtpk(e[0], e[1]),   R1 = cvtpk(e[2], e[3]);
        unsigned R2 = cvtpk(e[4], e[5]),   R3 = cvtpk(e[6], e[7]);
        unsigned R4 = cvtpk(e[8], e[9]),   R5 = cvtpk(e[10], e[11]);
        unsigned R6 = cvtpk(e[12], e[13]), R7 = cvtpk(e[14], e[15]);
        plswap(R0, R2); plswap(R1, R3); plswap(R4, R6); plswap(R5, R7);
        u32x4 w0v = { R0, R1, R2, R3 };
        u32x4 w1v = { R4, R5, R6, R7 };
        bf16x8 B0 = __builtin_bit_cast(bf16x8, w0v);   // m_local 0..15
        bf16x8 B1 = __builtin_bit_cast(bf16x8, w1v);   // m_local 16..31

        // ---- wave-local transpose read + wide store (4 x dwordx4)
        float* wp = wout + ((size_t)b * L_ + w * 512 + it * 32 + mr) * L_ + q0 + qc8;
        #pragma unroll
        for (int rr = 0; rr < 4; ++rr) {
            f32x4 v4 = *(const f32x4*)&wt[(mr + 8 * rr) * 36 + qc8];
            *(f32x4*)(wp + (size_t)(8 * rr) * L_) = v4;
        }

        // ---- PV (waits only on vf: older than this iter's stores in queue)
        pv0 = MFMA32(vf[0], B0, pv0, 0, 0, 0); pv1 = MFMA32(vf[2], B0, pv1, 0, 0, 0);
        pv2 = MFMA32(vf[4], B0, pv2, 0, 0, 0); pv3 = MFMA32(vf[6], B0, pv3, 0, 0, 0);
        pv0 = MFMA32(vf[1], B1, pv0, 0, 0, 0); pv1 = MFMA32(vf[3], B1, pv1, 0, 0, 0);
        pv2 = MFMA32(vf[5], B1, pv2, 0, 0, 0); pv3 = MFMA32(vf[7], B1, pv3, 0, 0, 0);
    }

    // ---------------- PV cross-wave reduce (4 -> 2 -> sum) ----------------
    __syncthreads();   // all waves done with wt region
    float* red0 = scratch;
    float* red1 = scratch + 128 * 36;
    if (w >= 2) {
        float* rp = ((w == 2) ? red0 : red1) + col;
        #pragma unroll
        for (int g = 0; g < 4; ++g)
            #pragma unroll
            for (int rr = 0; rr < 4; ++rr) {
                const int ol = rr + 8 * g + 4 * hl;
                rp[(ol)      * 36] = pv0[4 * g + rr];
                rp[(ol + 32) * 36] = pv1[4 * g + rr];
                rp[(ol + 64) * 36] = pv2[4 * g + rr];
                rp[(ol + 96) * 36] = pv3[4 * g + rr];
            }
    }
    __syncthreads();
    if (w < 2) {
        float* rp = ((w == 0) ? red0 : red1) + col;
        #pragma unroll
        for (int g = 0; g < 4; ++g)
            #pragma unroll
            for (int rr = 0; rr < 4; ++rr) {
                const int ol = rr + 8 * g + 4 * hl;
                rp[(ol)      * 36] += pv0[4 * g + rr];
                rp[(ol + 32) * 36] += pv1[4 * g + rr];
                rp[(ol + 64) * 36] += pv2[4 * g + rr];
                rp[(ol + 96) * 36] += pv3[4 * g + rr];
            }
    }
    __syncthreads();

    // ---------------- wide out-store ----------------
    {
        const int o8 = tid >> 3;          // 0..31
        const int qc = (tid & 7) * 4;
        const f32x4 rs4 = *(const f32x4*)&rsb[(size_t)b * L_ + q0 + qc];
        #pragma unroll
        for (int p = 0; p < 4; ++p) {
            const int o = o8 + 32 * p;
            f32x4 v0 = *(const f32x4*)&red0[o * 36 + qc];
            f32x4 v1 = *(const f32x4*)&red1[o * 36 + qc];
            f32x4 s  = (v0 + v1) * rs4;
            *(f32x4*)&out[((size_t)b * K_ + o) * L_ + q0 + qc] = s;
        }
    }
}

extern "C" void kernel_launch(void* const* d_in, const int* in_sizes, int n_in,
                              void* d_out, int out_size, void* d_ws, size_t ws_size,
                              hipStream_t stream) {
    (void)in_sizes; (void)n_in; (void)out_size; (void)ws_size;
    const float* x1 = (const float*)d_in[0];
    const float* x2 = (const float*)d_in[1];
    const float* Wq = (const float*)d_in[2];
    const float* bq = (const float*)d_in[3];
    const float* Wk = (const float*)d_in[4];
    const float* bk = (const float*)d_in[5];
    const float* Wv = (const float*)d_in[6];
    const float* bv = (const float*)d_in[7];

    float* out  = (float*)d_out;                       // (B,O,LQ) f32
    float* wout = out + (size_t)B_ * K_ * L_;          // (B,LK,LQ) f32

    const size_t NPROJ = (size_t)B_ * L_ * K_;         // 2,097,152
    u16* qF  = (u16*)d_ws;                             // fragment-ready
    u16* kF  = qF  + NPROJ;
    u16* vF  = kF  + NPROJ;
    float* rsb = (float*)(vF + NPROJ);                 // [b][q] = 1/colsum

    proj_kernel<<<dim3(768), 256, 0, stream>>>(
        x1, x2, Wq, bq, Wk, bk, Wv, bv, qF, kF, vF);

    rs_kernel<<<dim3(512), 256, 0, stream>>>(qF, kF, rsb);

    wpv_kernel<<<dim3(512), 256, 0, stream>>>(qF, kF, vF, rsb, out, wout);
}

// Round 10
// 56.493 us; speedup vs baseline: 1.1282x; 1.1282x over previous
//
#include <hip/hip_runtime.h>
#include <cstddef>

#define B_ 8
#define C_ 128
#define K_ 128
#define L_ 2048

static constexpr float SCALE = 0.08838834764831843f; // 1/sqrt(128)

typedef unsigned short u16;
typedef __attribute__((ext_vector_type(8))) short bf16x8;
typedef __attribute__((ext_vector_type(4))) unsigned short u16x4;
typedef __attribute__((ext_vector_type(4))) unsigned int u32x4;
typedef __attribute__((ext_vector_type(4))) float f32x4;
typedef __attribute__((ext_vector_type(16))) float f32x16;

__device__ __forceinline__ u16 f2bf(float x) {
    unsigned u = __builtin_bit_cast(unsigned, x);
    u += 0x7FFFu + ((u >> 16) & 1u);     // round-to-nearest-even
    return (u16)(u >> 16);
}

__device__ __forceinline__ unsigned cvtpk(float lo, float hi) {
    unsigned r;
    asm("v_cvt_pk_bf16_f32 %0, %1, %2" : "=v"(r) : "v"(lo), "v"(hi));
    return r;
}
// v_permlane32_swap_b32 a, b:  a' = {a.lo, b.lo},  b' = {a.hi, b.hi}
__device__ __forceinline__ void plswap(unsigned& a, unsigned& b) {
    asm volatile("v_permlane32_swap_b32 %0, %1" : "+v"(a), "+v"(b));
}

#define MFMA32 __builtin_amdgcn_mfma_f32_32x32x16_bf16

// Fragment-ready layouts (all loads are base + lane*16B):
//  qF/kF: [b][tile32][ks(8)][hl(2)][lane32][8]   tile = position/32, k = ks*16+hl*8+j
//  vF:    [b][mtile32][ob(4)][t(2)][hl(2)][lane32][8]
//         o = ob*32+lane, m = mtile*32 + t*16 + hl*8 + j

// ---------------------------------------------------------------------------
// K1: MFMA projections into fragment-ready layouts, x staged through LDS.
// grid 768 flattened: b = bid&7 (XCD-pinned so frag writes stay in the L2
// that the fused kernel for batch b reads), p = (bid>>3)>>5, l0 = ((bid>>3)&31)*64.
// block 256 = 4 waves.  (verified passing in round 7)
// ---------------------------------------------------------------------------
__global__ __launch_bounds__(256) void proj_kernel(
    const float* __restrict__ x1, const float* __restrict__ x2,
    const float* __restrict__ Wq, const float* __restrict__ bq,
    const float* __restrict__ Wk, const float* __restrict__ bk,
    const float* __restrict__ Wv, const float* __restrict__ bv,
    u16* __restrict__ qF, u16* __restrict__ kF, u16* __restrict__ vF)
{
    const int bid = blockIdx.x;
    const int b   = bid & 7;
    const int r   = bid >> 3;            // 0..95
    const int p   = r >> 5;              // 0..2
    const int l0  = (r & 31) * 64;
    const float* W    = (p == 0) ? Wq : (p == 1) ? Wk : Wv;
    const float* bias = (p == 0) ? bq : (p == 1) ? bk : bv;
    const float* X    = (p == 0) ? x1 : x2;

    __shared__ u16 Wls[128 * 136];   // [k][c], stride 136 shorts (pad 8)
    __shared__ u16 xls[64 * 136];    // [l_local][c], same padded stride
    const int tid = threadIdx.x;

    // ---- W staging (f32 -> bf16), coalesced float4
    for (int i = tid; i < 4096; i += 256) {
        float4 v = ((const float4*)W)[i];
        int e = i << 2; int row = e >> 7; int colc = e & 127;
        u16x4 pk = { f2bf(v.x), f2bf(v.y), f2bf(v.z), f2bf(v.w) };
        *(u16x4*)&Wls[row * 136 + colc] = pk;
    }

    // ---- x staging: read coalesced along l, write transposed bf16 tile [l][c]
    {
        const int lane = tid & 63;
        const int crow = tid >> 6;           // 4 c-rows in flight
        const float* xp = X + ((size_t)b * C_ + crow) * L_ + l0 + lane;
        #pragma unroll 4
        for (int c0 = crow; c0 < 128; c0 += 4) {
            xls[lane * 136 + c0] = f2bf(*xp);
            xp += 4 * (size_t)L_;
        }
    }
    __syncthreads();

    const int w = tid >> 6, l = tid & 63;
    const int lr = l & 15, lg = l >> 4;
    const int lrow = l0 + w * 16 + lr;       // global position
    const int lloc = w * 16 + lr;            // LDS-local row

    bf16x8 xfr[4];
    #pragma unroll
    for (int s = 0; s < 4; ++s)
        xfr[s] = *(const bf16x8*)&xls[lloc * 136 + s * 32 + lg * 8];

    const int hl2 = lg >> 1, j0 = (lg & 1) * 4;

    for (int kt = 0; kt < 8; ++kt) {
        bf16x8 wfr[4];
        #pragma unroll
        for (int s = 0; s < 4; ++s)
            wfr[s] = *(const bf16x8*)&Wls[(kt * 16 + lr) * 136 + s * 32 + lg * 8];
        f32x4 acc = {0.f, 0.f, 0.f, 0.f};
        if (p < 2) {
            // D[k][pos]: col(lr)=pos-local, row(lg*4+r)=k = kt*16+lg*4+r
            #pragma unroll
            for (int s = 0; s < 4; ++s)
                acc = __builtin_amdgcn_mfma_f32_16x16x32_bf16(wfr[s], xfr[s], acc, 0, 0, 0);
            u16x4 pk;
            #pragma unroll
            for (int rr = 0; rr < 4; ++rr)
                pk[rr] = f2bf(acc[rr] + bias[kt * 16 + lg * 4 + rr]);
            const int qt = lrow >> 5, qloc = lrow & 31;
            u16* dstp = ((p == 0) ? qF : kF)
                + (((size_t)b * 64 + qt) * 8 + kt) * 512 + hl2 * 256 + qloc * 8 + j0;
            *(u16x4*)dstp = pk;
        } else {
            // D[pos][o]: col(lr)=o-part, row(lg*4+r)=pos = lrow-part
            #pragma unroll
            for (int s = 0; s < 4; ++s)
                acc = __builtin_amdgcn_mfma_f32_16x16x32_bf16(xfr[s], wfr[s], acc, 0, 0, 0);
            const int o = kt * 16 + lr;
            const float bo = bias[o];
            u16x4 pk;
            #pragma unroll
            for (int rr = 0; rr < 4; ++rr)
                pk[rr] = f2bf(acc[rr] + bo);
            const int mt  = (l0 >> 5) + ((w * 16 + lg * 4) >> 5);
            const int t   = w & 1;
            const int ob  = kt >> 1;
            const int oloc = (kt & 1) * 16 + lr;
            u16* dstp = vF + ((size_t)b * 64 + mt) * 4096
                + ob * 1024 + t * 512 + hl2 * 256 + oloc * 8 + j0;
            *(u16x4*)dstp = pk;
        }
    }
}

// ---------------------------------------------------------------------------
// K2: fused single-QK attention (round-5 structure, verified 57.17 us).
//   grid 512 blocks (b = bid&7 -> XCD-pinned batch), block 512 = 8 waves.
//   Pass 1: QK + exp ONCE; packed-bf16 e kept in 64 VGPRs; csum -> rs.
//   Pass 2: PV from stored frags; w written via per-wave 32m x 32q LDS
//           transpose -> global_store_dwordx4 (store instrs/iter: 16 -> 4).
//   wtile region (36 KB) time-shares the 64 KB PV-reduce buffer.
// ---------------------------------------------------------------------------
__global__ __launch_bounds__(512, 2) void fused_attn_kernel(
    const u16* __restrict__ qF, const u16* __restrict__ kF,
    const u16* __restrict__ vF, float* __restrict__ out,
    float* __restrict__ wout)
{
    __shared__ float scratch[4 * 128 * 32];  // 64 KB: wtile during loop, red after
    __shared__ float cred[8 * 32];           // csum staging

    const int bid = blockIdx.x;
    const int b   = bid & 7;              // round-robin dispatch -> same b on same XCD
    const int qt  = bid >> 3;             // 0..63
    const int q0  = qt * 32;
    const int tid = threadIdx.x;
    const int w   = tid >> 6;             // 0..7
    const int l   = tid & 63;
    const int col = l & 31;
    const int hl  = l >> 5;

    // persistent Q B-frags (coalesced: lane-contiguous)
    bf16x8 qf[8];
    {
        const u16* qp = qF + (((size_t)b * 64 + qt) * 8) * 512 + l * 8;
        #pragma unroll
        for (int ks = 0; ks < 8; ++ks)
            qf[ks] = *(const bf16x8*)(qp + ks * 512);
    }

    const u16* kbase = kF + (((size_t)b * 64 + w * 8) * 8) * 512 + l * 8;
    const u16* vbase = vF + ((size_t)b * 64 + w * 8) * 4096 + l * 8;

    // packed post-swap e fragments: ePA[it] = m_local 0..15, ePB[it] = 16..31
    u32x4 ePA[8], ePB[8];
    float csum = 0.f;

    bf16x8 kA[8], kB[8];
    auto LK = [&](bf16x8 (&d)[8], int it) {
        const u16* ka = kbase + (size_t)it * 4096;
        #pragma unroll
        for (int j = 0; j < 8; ++j)
            d[j] = *(const bf16x8*)(ka + j * 512);
    };

    // ---------------- Pass 1: QK + exp + pack (once) ----------------
    LK(kA, 0);
    #pragma unroll
    for (int it = 0; it < 8; ++it) {
        bf16x8* kf = (it & 1) ? kB : kA;
        bf16x8 (&kn)[8] = (it & 1) ? kA : kB;
        f32x16 sa = {}, sb = {};
        sa = MFMA32(kf[0], qf[0], sa, 0, 0, 0); sb = MFMA32(kf[4], qf[4], sb, 0, 0, 0);
        sa = MFMA32(kf[1], qf[1], sa, 0, 0, 0); sb = MFMA32(kf[5], qf[5], sb, 0, 0, 0);
        sa = MFMA32(kf[2], qf[2], sa, 0, 0, 0); sb = MFMA32(kf[6], qf[6], sb, 0, 0, 0);
        sa = MFMA32(kf[3], qf[3], sa, 0, 0, 0); sb = MFMA32(kf[7], qf[7], sb, 0, 0, 0);
        if (it < 7) LK(kn, it + 1);

        float e[16];
        #pragma unroll
        for (int r = 0; r < 16; ++r)
            e[r] = __expf((sa[r] + sb[r]) * SCALE);
        float c0 = (e[0] + e[1]) + (e[2] + e[3]);
        float c1 = (e[4] + e[5]) + (e[6] + e[7]);
        float c2 = (e[8] + e[9]) + (e[10] + e[11]);
        float c3 = (e[12] + e[13]) + (e[14] + e[15]);
        csum += (c0 + c1) + (c2 + c3);

        unsigned R0 = cvtpk(e[0], e[1]),   R1 = cvtpk(e[2], e[3]);
        unsigned R2 = cvtpk(e[4], e[5]),   R3 = cvtpk(e[6], e[7]);
        unsigned R4 = cvtpk(e[8], e[9]),   R5 = cvtpk(e[10], e[11]);
        unsigned R6 = cvtpk(e[12], e[13]), R7 = cvtpk(e[14], e[15]);
        plswap(R0, R2); plswap(R1, R3); plswap(R4, R6); plswap(R5, R7);
        ePA[it] = u32x4{ R0, R1, R2, R3 };   // B0: m_local = hl*8 + j
        ePB[it] = u32x4{ R4, R5, R6, R7 };   // B1: m_local = 16 + hl*8 + j
    }

    // ---------------- csum reduce -> rs ----------------
    csum += __shfl_xor(csum, 32);
    if (hl == 0) cred[w * 32 + col] = csum;
    __syncthreads();
    const float rs = 1.0f / (((cred[col]       + cred[32 + col])
                            + (cred[64 + col]  + cred[96 + col]))
                           + ((cred[128 + col] + cred[160 + col])
                            + (cred[192 + col] + cred[224 + col])));

    // ---------------- Pass 2: PV + wide w-write (no QK) ----------------
    f32x16 pv0 = {}, pv1 = {}, pv2 = {}, pv3 = {};

    float* wt = scratch + w * 1152;       // per-wave 32 x 36 f32 tile (16B-aligned rows)
    const int mr = l >> 3;                // 0..7  (store row within 8-row group)
    const int qc = (l & 7) * 4;           // 0,4,...,28 (4 consecutive q per lane)

    bf16x8 vA[8], vB[8];
    auto LV = [&](bf16x8 (&d)[8], int it) {
        const u16* va = vbase + (size_t)it * 4096;
        #pragma unroll
        for (int j = 0; j < 8; ++j)
            d[j] = *(const bf16x8*)(va + j * 512);   // d[2s+t] = (ob=s, t)
    };

    LV(vA, 0);
    #pragma unroll
    for (int it = 0; it < 8; ++it) {
        bf16x8* vf = (it & 1) ? vB : vA;
        bf16x8 (&vn)[8] = (it & 1) ? vA : vB;
        if (it < 7) LV(vn, it + 1);

        bf16x8 B0 = __builtin_bit_cast(bf16x8, ePA[it]);
        bf16x8 B1 = __builtin_bit_cast(bf16x8, ePB[it]);

        pv0 = MFMA32(vf[0], B0, pv0, 0, 0, 0); pv1 = MFMA32(vf[2], B0, pv1, 0, 0, 0);
        pv2 = MFMA32(vf[4], B0, pv2, 0, 0, 0); pv3 = MFMA32(vf[6], B0, pv3, 0, 0, 0);
        pv0 = MFMA32(vf[1], B1, pv0, 0, 0, 0); pv1 = MFMA32(vf[3], B1, pv1, 0, 0, 0);
        pv2 = MFMA32(vf[5], B1, pv2, 0, 0, 0); pv3 = MFMA32(vf[7], B1, pv3, 0, 0, 0);

        // unpack e*rs into per-wave LDS tile wt[m_local][col]
        #pragma unroll
        for (int d = 0; d < 4; ++d) {
            const unsigned da = ePA[it][d], db = ePB[it][d];
            wt[(hl * 8 + 2 * d)          * 36 + col] =
                __builtin_bit_cast(float, da << 16) * rs;
            wt[(hl * 8 + 2 * d + 1)      * 36 + col] =
                __builtin_bit_cast(float, da & 0xFFFF0000u) * rs;
            wt[(16 + hl * 8 + 2 * d)     * 36 + col] =
                __builtin_bit_cast(float, db << 16) * rs;
            wt[(16 + hl * 8 + 2 * d + 1) * 36 + col] =
                __builtin_bit_cast(float, db & 0xFFFF0000u) * rs;
        }

        // wave-local transpose read + wide store: 4 x dwordx4 (1 KB/instr)
        float* wp = wout + ((size_t)b * L_ + w * 256 + it * 32 + mr) * L_ + q0 + qc;
        #pragma unroll
        for (int rr = 0; rr < 4; ++rr) {
            f32x4 v4 = *(const f32x4*)&wt[(mr + 8 * rr) * 36 + qc];
            *(f32x4*)(wp + (size_t)(8 * rr) * L_) = v4;
        }
    }

    // ---------------- PV cross-wave reduce (8 -> 4 -> 1) ----------------
    float* red = scratch;
    __syncthreads();   // all waves done with wtile region before red reuse
    if (w >= 4) {
        float* rp = red + (size_t)(w - 4) * 128 * 32 + col;
        #pragma unroll
        for (int g = 0; g < 4; ++g)
            #pragma unroll
            for (int rr = 0; rr < 4; ++rr) {
                const int ol = rr + 8 * g + 4 * hl;
                rp[(ol)      * 32] = pv0[4 * g + rr];
                rp[(ol + 32) * 32] = pv1[4 * g + rr];
                rp[(ol + 64) * 32] = pv2[4 * g + rr];
                rp[(ol + 96) * 32] = pv3[4 * g + rr];
            }
    }
    __syncthreads();
    if (w < 4) {
        float* rp = red + (size_t)w * 128 * 32 + col;
        #pragma unroll
        for (int g = 0; g < 4; ++g)
            #pragma unroll
            for (int rr = 0; rr < 4; ++rr) {
                const int ol = rr + 8 * g + 4 * hl;
                rp[(ol)      * 32] += pv0[4 * g + rr];
                rp[(ol + 32) * 32] += pv1[4 * g + rr];
                rp[(ol + 64) * 32] += pv2[4 * g + rr];
                rp[(ol + 96) * 32] += pv3[4 * g + rr];
            }
    }
    __syncthreads();

    {
        const int qq = tid & 31;          // == col, so this thread's rs matches qq
        const int og = tid >> 5;          // 0..15
        float* ob = out + ((size_t)b * K_) * L_ + q0 + qq;
        #pragma unroll
        for (int i = 0; i < 8; ++i) {
            const int o = og + 16 * i;
            const float v = red[(0 * 128 + o) * 32 + qq] + red[(1 * 128 + o) * 32 + qq]
                          + red[(2 * 128 + o) * 32 + qq] + red[(3 * 128 + o) * 32 + qq];
            ob[(size_t)o * L_] = v * rs;
        }
    }
}

extern "C" void kernel_launch(void* const* d_in, const int* in_sizes, int n_in,
                              void* d_out, int out_size, void* d_ws, size_t ws_size,
                              hipStream_t stream) {
    (void)in_sizes; (void)n_in; (void)out_size; (void)ws_size;
    const float* x1 = (const float*)d_in[0];
    const float* x2 = (const float*)d_in[1];
    const float* Wq = (const float*)d_in[2];
    const float* bq = (const float*)d_in[3];
    const float* Wk = (const float*)d_in[4];
    const float* bk = (const float*)d_in[5];
    const float* Wv = (const float*)d_in[6];
    const float* bv = (const float*)d_in[7];

    float* out  = (float*)d_out;                       // (B,O,LQ) f32
    float* wout = out + (size_t)B_ * K_ * L_;          // (B,LK,LQ) f32

    const size_t NPROJ = (size_t)B_ * L_ * K_;         // 2,097,152
    u16* qF  = (u16*)d_ws;                             // fragment-ready
    u16* kF  = qF  + NPROJ;
    u16* vF  = kF  + NPROJ;

    proj_kernel<<<dim3(768), 256, 0, stream>>>(
        x1, x2, Wq, bq, Wk, bk, Wv, bv, qF, kF, vF);

    fused_attn_kernel<<<dim3(512), 512, 0, stream>>>(qF, kF, vF, out, wout);
}